// Round 14
// baseline (2047.927 us; speedup 1.0000x reference)
//
#include <hip/hip_runtime.h>
#include <hip/hip_bf16.h>

typedef unsigned short u16;
typedef short bf16x8 __attribute__((ext_vector_type(8)));
typedef u16 u16x8 __attribute__((ext_vector_type(8)));
typedef float f32x4 __attribute__((ext_vector_type(4)));
typedef float f32x16 __attribute__((ext_vector_type(16)));

#define DEV __device__ __forceinline__

DEV u16 f2bf(float f) {
  union { float f; unsigned u; } a; a.f = f;
  unsigned r = a.u + 0x7FFFu + ((a.u >> 16) & 1u);
  return (u16)(r >> 16);
}
DEV float bf2f(u16 u) {
  union { unsigned u; float f; } a; a.u = ((unsigned)u) << 16; return a.f;
}
DEV float ftanh(float v) {               // exp-based tanh; saturates correctly
  float e = __expf(2.f * v);
  return 1.f - 2.f / (e + 1.f);
}
DEV void async16(const void* g, void* l) {
  __builtin_amdgcn_global_load_lds(
      (const __attribute__((address_space(1))) unsigned int*)g,
      (__attribute__((address_space(3))) unsigned int*)l, 16, 0, 0);
}

#define SBAR() asm volatile("s_barrier" ::: "memory")
#define WAITV(n) asm volatile("s_waitcnt vmcnt(" #n ")" ::: "memory")

// ---------------- transpose + cvt: fp32 [K][N] -> bf16 [N][K] (Plan C) ----------------
__global__ __launch_bounds__(256) void transpose_cvt(const float* __restrict__ in,
                                                     u16* __restrict__ out, int K, int N) {
  __shared__ float tile[32][33];
  const int kt = blockIdx.y * 32, nt = blockIdx.x * 32;
  const int tx = threadIdx.x & 31, ty = threadIdx.x >> 5;
#pragma unroll
  for (int i = 0; i < 32; i += 8) {
    int k = kt + ty + i, n = nt + tx;
    tile[ty + i][tx] = (k < K && n < N) ? in[(long)k * N + n] : 0.f;
  }
  __syncthreads();
#pragma unroll
  for (int i = 0; i < 32; i += 8) {
    int n = nt + ty + i, k = kt + tx;
    if (n < N && k < K) out[(long)n * K + k] = f2bf(tile[tx][ty + i]);
  }
}

// ---------------- prep: concat + clip -> bf16 [R][768] ----------------
__global__ __launch_bounds__(256) void prep_kernel(const float* __restrict__ state,
                                                   const float* __restrict__ cond,
                                                   u16* __restrict__ xb) {
  int idx = blockIdx.x * 256 + threadIdx.x;
  int t = idx / 192, c4 = idx - t * 192;
  float4 v;
  if (c4 < 128) v = ((const float4*)state)[(long)t * 128 + c4];
  else          v = ((const float4*)cond)[(long)t * 64 + (c4 - 128)];
  ushort4 o;
  o.x = f2bf(fminf(fmaxf(v.x, -16.f), 16.f));
  o.y = f2bf(fminf(fmaxf(v.y, -16.f), 16.f));
  o.z = f2bf(fminf(fmaxf(v.z, -16.f), 16.f));
  o.w = f2bf(fminf(fmaxf(v.w, -16.f), 16.f));
  *(ushort4*)(xb + (long)t * 768 + c4 * 4) = o;
}

// ---------------- merged init: 11 weight transposes + prep in ONE launch ----------------
struct WSrc { const float* p[11]; };
__global__ __launch_bounds__(256) void init_kernel(WSrc src, u16* __restrict__ wt,
                                                   const float* __restrict__ state,
                                                   const float* __restrict__ cond,
                                                   u16* __restrict__ xb) {
  __shared__ float tile[32][33];
  const int b = blockIdx.x;
  if (b >= 8480) {  // prep job
    int idx = (b - 8480) * 256 + threadIdx.x;
    int t = idx / 192, c4 = idx - t * 192;
    float4 v;
    if (c4 < 128) v = ((const float4*)state)[(long)t * 128 + c4];
    else          v = ((const float4*)cond)[(long)t * 64 + (c4 - 128)];
    ushort4 o;
    o.x = f2bf(fminf(fmaxf(v.x, -16.f), 16.f));
    o.y = f2bf(fminf(fmaxf(v.y, -16.f), 16.f));
    o.z = f2bf(fminf(fmaxf(v.z, -16.f), 16.f));
    o.w = f2bf(fminf(fmaxf(v.w, -16.f), 16.f));
    *(ushort4*)(xb + (long)t * 768 + c4 * 4) = o;
    return;
  }
  int job, base, K, N, X;
  long off;
  if      (b < 768)  { job = 0;  base = 0;    K = 768;  N = 1024; X = 32; off = 0; }
  else if (b < 1536) { job = 1;  base = 768;  K = 768;  N = 1024; X = 32; off = 786432; }
  else if (b < 2560) { job = 2;  base = 1536; K = 1024; N = 1024; X = 32; off = 1572864; }
  else if (b < 2592) { job = 3;  base = 2560; K = 256;  N = 128;  X = 4;  off = 2621440; }
  else if (b < 2848) { job = 4;  base = 2592; K = 128;  N = 2048; X = 64; off = 2654208; }
  else if (b < 3872) { job = 5;  base = 2848; K = 1024; N = 1024; X = 32; off = 2916352; }
  else if (b < 4896) { job = 6;  base = 3872; K = 1024; N = 1024; X = 32; off = 3964928; }
  else if (b < 5920) { job = 7;  base = 4896; K = 1024; N = 1024; X = 32; off = 5013504; }
  else if (b < 6944) { job = 8;  base = 5920; K = 1024; N = 1024; X = 32; off = 6062080; }
  else if (b < 7968) { job = 9;  base = 6944; K = 1024; N = 1024; X = 32; off = 7110656; }
  else               { job = 10; base = 7968; K = 1024; N = 512;  X = 16; off = 8159232; }
  const float* in = src.p[job];
  u16* out = wt + off;
  const int lb = b - base;
  const int kt = (lb / X) * 32, nt = (lb % X) * 32;
  const int tx = threadIdx.x & 31, ty = threadIdx.x >> 5;
#pragma unroll
  for (int i = 0; i < 32; i += 8) {
    int k = kt + ty + i, n = nt + tx;
    tile[ty + i][tx] = (k < K && n < N) ? in[(long)k * N + n] : 0.f;
  }
  __syncthreads();
#pragma unroll
  for (int i = 0; i < 32; i += 8) {
    int n = nt + ty + i, k = kt + tx;
    if (n < N && k < K) out[(long)n * K + k] = f2bf(tile[tx][ty + i]);
  }
}

// ---------------- per-wave reduce ----------------
DEV void wreduce2(float& s, float& q) {
#pragma unroll
  for (int off = 32; off; off >>= 1) { s += __shfl_xor(s, off); q += __shfl_xor(q, off); }
}

// ---------------- per-wave LN+ReLU: 1 wave = 1 row; in-place safe ----------------
__global__ __launch_bounds__(256) void ln_relu_w(const u16* in,
                                                 const float* __restrict__ g,
                                                 const float* __restrict__ bt,
                                                 u16* out) {
  const int wid = threadIdx.x >> 6, lane = threadIdx.x & 63;
  const long row = (long)blockIdx.x * 4 + wid;
  const u16* ip = in + row * 1024 + lane * 16;
  u16x8 v0 = *(const u16x8*)ip;
  u16x8 v1 = *(const u16x8*)(ip + 8);
  float x[16];
#pragma unroll
  for (int j = 0; j < 8; ++j) { x[j] = bf2f(v0[j]); x[8 + j] = bf2f(v1[j]); }
  float s = 0.f, q = 0.f;
#pragma unroll
  for (int j = 0; j < 16; ++j) { s += x[j]; q += x[j] * x[j]; }
  wreduce2(s, q);
  float mean = s * (1.f / 1024.f);
  float var  = q * (1.f / 1024.f) - mean * mean;
  float rs   = rsqrtf(var + 1e-5f);
  const int c0 = lane * 16;
  float4 g0 = *(const float4*)(g + c0),      g1 = *(const float4*)(g + c0 + 4);
  float4 g2 = *(const float4*)(g + c0 + 8),  g3 = *(const float4*)(g + c0 + 12);
  float4 b0 = *(const float4*)(bt + c0),     b1 = *(const float4*)(bt + c0 + 4);
  float4 b2 = *(const float4*)(bt + c0 + 8), b3 = *(const float4*)(bt + c0 + 12);
  float ga[16] = {g0.x,g0.y,g0.z,g0.w, g1.x,g1.y,g1.z,g1.w, g2.x,g2.y,g2.z,g2.w, g3.x,g3.y,g3.z,g3.w};
  float ba[16] = {b0.x,b0.y,b0.z,b0.w, b1.x,b1.y,b1.z,b1.w, b2.x,b2.y,b2.z,b2.w, b3.x,b3.y,b3.z,b3.w};
  u16x8 o0, o1;
#pragma unroll
  for (int j = 0; j < 8; ++j) {
    o0[j] = f2bf(fmaxf((x[j] - mean) * rs * ga[j] + ba[j], 0.f));
    o1[j] = f2bf(fmaxf((x[8 + j] - mean) * rs * ga[8 + j] + ba[8 + j], 0.f));
  }
  u16* op = out + row * 1024 + lane * 16;
  *(u16x8*)op = o0;
  *(u16x8*)(op + 8) = o1;
}

// ---------------- per-wave h2 = LN(h + o2) ----------------
__global__ __launch_bounds__(256) void h2_w(const u16* __restrict__ h,
                                            const u16* o2,
                                            const float* __restrict__ g,
                                            const float* __restrict__ bt,
                                            u16* out) {
  const int wid = threadIdx.x >> 6, lane = threadIdx.x & 63;
  const long row = (long)blockIdx.x * 4 + wid;
  const u16* hp = h + row * 1024 + lane * 16;
  const u16* op2 = o2 + row * 1024 + lane * 16;
  u16x8 a0 = *(const u16x8*)hp,  a1 = *(const u16x8*)(hp + 8);
  u16x8 c0v = *(const u16x8*)op2, c1v = *(const u16x8*)(op2 + 8);
  float x[16];
#pragma unroll
  for (int j = 0; j < 8; ++j) {
    x[j]     = bf2f(a0[j]) + bf2f(c0v[j]);
    x[8 + j] = bf2f(a1[j]) + bf2f(c1v[j]);
  }
  float s = 0.f, q = 0.f;
#pragma unroll
  for (int j = 0; j < 16; ++j) { s += x[j]; q += x[j] * x[j]; }
  wreduce2(s, q);
  float mean = s * (1.f / 1024.f);
  float var  = q * (1.f / 1024.f) - mean * mean;
  float rs   = rsqrtf(var + 1e-5f);
  const int cc = lane * 16;
  u16x8 o0, o1;
#pragma unroll
  for (int j = 0; j < 8; ++j) {
    o0[j] = f2bf((x[j] - mean) * rs * g[cc + j] + bt[cc + j]);
    o1[j] = f2bf((x[8 + j] - mean) * rs * g[cc + 8 + j] + bt[cc + 8 + j]);
  }
  u16* op = out + row * 1024 + lane * 16;
  *(u16x8*)op = o0;
  *(u16x8*)(op + 8) = o1;
}

// ---------------- qin with separate gain/bias (Plan C; qout may alias gain) ----------------
__global__ __launch_bounds__(256) void qin_sep_kernel(const u16* __restrict__ h,
                                                      const u16* gain, const u16* bias,
                                                      const float* __restrict__ lg,
                                                      const float* __restrict__ lbt,
                                                      u16* qout) {
  __shared__ float sh[8];
  const long row = blockIdx.x;
  const int tid = threadIdx.x;
  ushort4 hv = *(const ushort4*)(h + row * 1024 + tid * 4);
  float x[4] = {bf2f(hv.x), bf2f(hv.y), bf2f(hv.z), bf2f(hv.w)};
  float s = x[0] + x[1] + x[2] + x[3];
  float q = x[0]*x[0] + x[1]*x[1] + x[2]*x[2] + x[3]*x[3];
#pragma unroll
  for (int off = 32; off; off >>= 1) { s += __shfl_xor(s, off); q += __shfl_xor(q, off); }
  const int w = tid >> 6;
  if ((tid & 63) == 0) { sh[w] = s; sh[4 + w] = q; }
  __syncthreads();
  s = sh[0] + sh[1] + sh[2] + sh[3];
  q = sh[4] + sh[5] + sh[6] + sh[7];
  float mean = s * (1.f / 1024.f);
  float var  = q * (1.f / 1024.f) - mean * mean;
  float rs   = rsqrtf(var + 1e-5f);
  ushort4 gv = *(const ushort4*)(gain + row * 1024 + tid * 4);
  ushort4 bv = *(const ushort4*)(bias + row * 1024 + tid * 4);
  const u16* gp = (const u16*)&gv;
  const u16* bp = (const u16*)&bv;
  ushort4 ov; u16* op = (u16*)&ov;
#pragma unroll
  for (int j = 0; j < 4; ++j) {
    int c = tid * 4 + j;
    float y = (x[j] - mean) * rs * lg[c] + lbt[c];
    op[j] = f2bf(y * bf2f(gp[j]) + bf2f(bp[j]));
  }
  *(ushort4*)(qout + row * 1024 + tid * 4) = ov;
}

// ============ fused FiLM + qin ============
__global__ __launch_bounds__(256) void film_qin(const u16* __restrict__ hbf,
                                                const u16* __restrict__ fh,
                                                const u16* __restrict__ fw2T,
                                                const float* __restrict__ fb2,
                                                const float* __restrict__ lg,
                                                const float* __restrict__ lbt,
                                                u16* __restrict__ qout) {
  extern __shared__ char lds[];
  u16* H = (u16*)lds;                 // [32][1024]
  char* Afh = lds + 65536;            // 8 KB swizzled [32][128] bf16
  float* sLN = (float*)(lds + 73728); // [32][2]
  const int tid = threadIdx.x;
  const int wid = tid >> 6, lane = tid & 63;
  const int fr = lane & 15, fq = lane >> 4;
  const long rows0 = (long)blockIdx.x * 32;

  {
    const int row = tid >> 3;
    const int inner = (tid & 7) * 32;
    const u16* src = fh + (rows0 + row) * 128 + (tid & 7) * 16;
    u16x8 f0 = *(const u16x8*)src;
    u16x8 f1 = *(const u16x8*)(src + 8);
    *(u16x8*)(Afh + row * 256 + ((inner)      ^ ((row & 7) << 4))) = f0;
    *(u16x8*)(Afh + row * 256 + ((inner + 16) ^ ((row & 7) << 4))) = f1;
  }

#pragma unroll
  for (int i = 0; i < 8; ++i) {
    const int row = i * 4 + wid;
    const u16* src = hbf + (rows0 + row) * 1024 + lane * 16;
    u16x8 v0 = *(const u16x8*)src;
    u16x8 v1 = *(const u16x8*)(src + 8);
    *(u16x8*)(H + row * 1024 + lane * 16) = v0;
    *(u16x8*)(H + row * 1024 + lane * 16 + 8) = v1;
    float s = 0.f, q = 0.f;
#pragma unroll
    for (int j = 0; j < 8; ++j) {
      float x0 = bf2f(v0[j]), x1 = bf2f(v1[j]);
      s += x0 + x1; q += x0 * x0 + x1 * x1;
    }
    wreduce2(s, q);
    if (lane == 0) {
      float mean = s * (1.f / 1024.f);
      float var  = q * (1.f / 1024.f) - mean * mean;
      sLN[row * 2] = mean;
      sLN[row * 2 + 1] = rsqrtf(var + 1e-5f);
    }
  }
  __syncthreads();

  const int cbase = wid * 256;
#pragma unroll 1
  for (int c8 = 0; c8 < 16; ++c8) {
    const int c = cbase + c8 * 16;
    const int col = c + fr;
    f32x4 ag[2] = {{0.f,0.f,0.f,0.f},{0.f,0.f,0.f,0.f}};
    f32x4 ab[2] = {{0.f,0.f,0.f,0.f},{0.f,0.f,0.f,0.f}};
#pragma unroll
    for (int ks = 0; ks < 4; ++ks) {
      bf16x8 bg = *(const bf16x8*)(fw2T + (long)col * 128 + ks * 32 + fq * 8);
      bf16x8 bb = *(const bf16x8*)(fw2T + (long)(1024 + col) * 128 + ks * 32 + fq * 8);
#pragma unroll
      for (int t = 0; t < 2; ++t) {
        const int row = t * 16 + fr;
        bf16x8 av = *(const bf16x8*)(Afh + row * 256 + ((ks * 64 + fq * 16) ^ ((fr & 7) << 4)));
        ag[t] = __builtin_amdgcn_mfma_f32_16x16x32_bf16(av, bg, ag[t], 0, 0, 0);
        ab[t] = __builtin_amdgcn_mfma_f32_16x16x32_bf16(av, bb, ab[t], 0, 0, 0);
      }
    }
    const float fg = fb2[col], fb = fb2[1024 + col];
    const float lgc = lg[col], lbc = lbt[col];
#pragma unroll
    for (int t = 0; t < 2; ++t)
#pragma unroll
      for (int r = 0; r < 4; ++r) {
        const int row = t * 16 + fq * 4 + r;
        float gv = 1.f + 0.5f * ftanh(ag[t][r] + fg);
        float bv = 0.5f * ftanh(ab[t][r] + fb);
        float x = bf2f(H[row * 1024 + col]);
        float y = (x - sLN[row * 2]) * sLN[row * 2 + 1] * lgc + lbc;
        H[row * 1024 + col] = f2bf(y * gv + bv);
      }
  }
  __syncthreads();

#pragma unroll
  for (int i = 0; i < 8; ++i) {
    const int row = i * 4 + wid;
    u16* dst = qout + (rows0 + row) * 1024 + lane * 16;
    *(u16x8*)dst = *(const u16x8*)(H + row * 1024 + lane * 16);
    *(u16x8*)(dst + 8) = *(const u16x8*)(H + row * 1024 + lane * 16 + 8);
  }
}

// ============ 128x128 GEMM (FiLM1 + Plan C) ============
template <int EPI>
__global__ __launch_bounds__(256) void gemm_bt(const u16* __restrict__ A,
                                               const u16* __restrict__ Bt,
                                               const float* __restrict__ bias,
                                               const u16* addend,
                                               u16* Co, float* Cf,
                                               int N, int K, int lda) {
  __shared__ u16 As[128 * 64];
  __shared__ u16 Bs[128 * 64];
  const int tid = threadIdx.x;
  const int w = tid >> 6, l = tid & 63;
  const int wr = w >> 1, wc = w & 1;
  const long bRow = (long)blockIdx.x * 128;
  const long bCol = (long)blockIdx.y * 128;

  f32x4 acc[4][4];
#pragma unroll
  for (int mi = 0; mi < 4; ++mi)
#pragma unroll
    for (int ni = 0; ni < 4; ++ni) acc[mi][ni] = (f32x4){0.f, 0.f, 0.f, 0.f};

  const int arow = l >> 3;
  const int acol = (l & 7) * 8;
  const u16* gA = A + (bRow + w * 8 + arow) * (long)lda + acol;
  const u16* gB = Bt + (bCol + w * 8 + arow) * (long)K + acol;

  const int fr = l & 15;
  const int fks = (l >> 4) * 8;

  for (int kt = 0; kt < K; kt += 64) {
#pragma unroll
    for (int i = 0; i < 4; ++i) {
      async16(gA + (long)i * 32 * lda + kt, As + (i * 32 + w * 8) * 64);
      async16(gB + (long)i * 32 * K   + kt, Bs + (i * 32 + w * 8) * 64);
    }
    __syncthreads();
#pragma unroll
    for (int kk = 0; kk < 2; ++kk) {
      const int ko = kk * 32 + fks;
      bf16x8 af[4], bff[4];
#pragma unroll
      for (int mi = 0; mi < 4; ++mi)
        af[mi] = *(const bf16x8*)(As + (wr * 64 + mi * 16 + fr) * 64 + ko);
#pragma unroll
      for (int ni = 0; ni < 4; ++ni)
        bff[ni] = *(const bf16x8*)(Bs + (wc * 64 + ni * 16 + fr) * 64 + ko);
#pragma unroll
      for (int mi = 0; mi < 4; ++mi)
#pragma unroll
        for (int ni = 0; ni < 4; ++ni)
          acc[mi][ni] = __builtin_amdgcn_mfma_f32_16x16x32_bf16(af[mi], bff[ni], acc[mi][ni], 0, 0, 0);
    }
    __syncthreads();
  }

  const int fq = l >> 4;
#pragma unroll
  for (int ni = 0; ni < 4; ++ni) {
    const long col = bCol + wc * 64 + ni * 16 + fr;
    const float bs = bias ? bias[col] : 0.f;
#pragma unroll
    for (int mi = 0; mi < 4; ++mi) {
#pragma unroll
      for (int r = 0; r < 4; ++r) {
        const long row = bRow + wr * 64 + mi * 16 + fq * 4 + r;
        float v = acc[mi][ni][r] + bs;
        if (EPI == 1) v = 0.5f * v * (1.f + erff(v * 0.70710678118654752f));
        else if (EPI == 2) v = 1.f + 0.5f * ftanh(v);
        else if (EPI == 3) v = fmaxf(v, 0.f);
        else if (EPI == 5) v += bf2f(addend[row * N + col]);
        else if (EPI == 6) v = 0.5f * ftanh(v);
        if (EPI == 4) Cf[row * N + col] = v;
        else          Co[row * N + col] = f2bf(v);
      }
    }
  }
}

// ============ 256x256 / BK=64 / 4-merged-phase GEMM, 32x32x16 MFMA port ============
// Round-14: same proven round-9 schedule (barriers/vmcnt/stage order identical);
// only the MFMA shape changes 16x16x32 -> 32x32x16 (matrix-pipe -13%, half the
// MFMA instructions). Operand/C layouts mirror the passing attn4 kernel:
// A/B frag: lane&31 = row/col, k = ks*16 + (lane>>5)*8 (8 contiguous bf16);
// C: col = lane&31, row = (r&3) + 8*(r>>2) + 4*(lane>>5), r in [0,16).
// Frag regs: a[4][2]=32 + b0[4]=16 + b1[4]=16 = 64 (same as round-9). acc=128.

#define RDA(buf, Qr) do { \
  _Pragma("unroll") for (int ks_ = 0; ks_ < 4; ++ks_) \
  _Pragma("unroll") for (int m_ = 0; m_ < 2; ++m_) \
    a[ks_][m_] = *(const bf16x8*)(ldsc + (buf) * 32768 + \
      ((Qr) * 128 + wr * 64 + m_ * 32 + lo) * 128 + ((ks_ * 32 + hi * 16) ^ swzc)); \
} while (0)

#define RDB(buf, Qc, bb) do { \
  _Pragma("unroll") for (int ks_ = 0; ks_ < 4; ++ks_) \
    bb[ks_] = *(const bf16x8*)(ldsc + 65536 + (buf) * 32768 + \
      ((Qc) * 128 + wc * 32 + lo) * 128 + ((ks_ * 32 + hi * 16) ^ swzc)); \
} while (0)

#define MM(Qr, Qc, bb) do { \
  __builtin_amdgcn_s_setprio(1); \
  _Pragma("unroll") for (int m_ = 0; m_ < 2; ++m_) \
  _Pragma("unroll") for (int ks_ = 0; ks_ < 4; ++ks_) \
    acc[Qr][Qc][m_] = __builtin_amdgcn_mfma_f32_32x32x16_bf16( \
        a[ks_][m_], bb[ks_], acc[Qr][Qc][m_], 0, 0, 0); \
  __builtin_amdgcn_s_setprio(0); \
} while (0)

#define STA(buf, tt, h) do { \
  _Pragma("unroll") for (int j_ = 0; j_ < 2; ++j_) \
    async16(aB + ((long)j_ * 64 + (h) * 128) * lda_l + (tt) * 64, \
            ldsc + (buf) * 32768 + (h) * 16384 + (j_ * 512 + tid) * 16); \
} while (0)

#define STB(buf, tt, h) do { \
  _Pragma("unroll") for (int j_ = 0; j_ < 2; ++j_) \
    async16(bB + ((long)j_ * 64 + (h) * 128) * K_l + (tt) * 64, \
            ldsc + 65536 + (buf) * 32768 + (h) * 16384 + (j_ * 512 + tid) * 16); \
} while (0)

template <int EPI>
__global__ __launch_bounds__(512, 2) void gemm256(const u16* __restrict__ A,
                                                  const u16* __restrict__ Bt,
                                                  const float* __restrict__ bias,
                                                  const u16* addend,
                                                  u16* Co, u16* Co2, float* Cf,
                                                  int N, int K, int lda, int ctLog) {
  extern __shared__ char ldsc[];
  const int tid = threadIdx.x;
  const int l = tid & 63;
  const int w = tid >> 6, wr = w >> 2, wc = w & 3;
  const int lo = l & 31, hi = l >> 5;
  const int swzc = (lo & 7) << 4;
  const long lda_l = lda, K_l = K;

  const int nwg = gridDim.x;
  const int orig = blockIdx.x;
  const int swz = (orig & 7) * (nwg >> 3) + (orig >> 3);
  const int rt = swz >> ctLog, ct = swz & ((1 << ctLog) - 1);
  const long bRow = (long)rt * 256, bCol = (long)ct * 256;
  const int NT = K >> 6;

  const int L0 = tid * 16;
  const int row0 = L0 >> 7;
  const int cswz = (L0 & 127) ^ ((row0 & 7) << 4);
  const u16* aB = A + (bRow + row0) * lda_l + (cswz >> 1);
  const u16* bB = Bt + (bCol + row0) * K_l + (cswz >> 1);

  f32x16 acc[2][2][2];
#pragma unroll
  for (int p = 0; p < 2; ++p)
#pragma unroll
    for (int qq = 0; qq < 2; ++qq)
#pragma unroll
      for (int m = 0; m < 2; ++m)
#pragma unroll
        for (int r = 0; r < 16; ++r) acc[p][qq][m][r] = 0.f;

  bf16x8 a[4][2], b0[4], b1[4];

  // prologue: tile0 full + tile1 A-h0, B-h1 (invariant: 4 loads in flight)
  STA(0, 0, 0); STA(0, 0, 1); STB(0, 0, 0); STB(0, 0, 1);
  STA(1, 1, 0); STB(1, 1, 1);
  WAITV(4);
  SBAR();

  for (int i = 0; i < (NT >> 1); ++i) {
    const int t0 = 2 * i, t1 = t0 + 1;
    const bool more = (t0 + 2) < NT;
    // phA: tile t0 (buf0) quadrants (0,0)+(0,1); stage t1's A-h1, B-h0
    RDA(0, 0); RDB(0, 0, b0); RDB(0, 1, b1);
    STA(1, t1, 1); STB(1, t1, 0);
    SBAR(); MM(0, 0, b0); MM(0, 1, b1); SBAR();
    // phB: quadrants (1,1)+(1,0); stage t0+2's A-h0, B-h1 into buf0
    RDA(0, 1);
    if (more) { STA(0, t0 + 2, 0); STB(0, t0 + 2, 1); }
    SBAR(); MM(1, 1, b1); MM(1, 0, b0);
    if (more) { WAITV(4); } else { WAITV(0); }   // tile t1 (buf1) complete
    SBAR();
    // phC: tile t1 (buf1) quadrants (0,0)+(0,1); stage t0+2's A-h1, B-h0
    RDA(1, 0); RDB(1, 0, b0); RDB(1, 1, b1);
    if (more) { STA(0, t0 + 2, 1); STB(0, t0 + 2, 0); }
    SBAR(); MM(0, 0, b0); MM(0, 1, b1); SBAR();
    // phD: quadrants (1,1)+(1,0); stage t1+2's A-h0, B-h1 into buf1
    RDA(1, 1);
    if (more) { STA(1, t1 + 2, 0); STB(1, t1 + 2, 1); }
    SBAR(); MM(1, 1, b1); MM(1, 0, b0);
    if (more) { WAITV(4); } else { WAITV(0); }   // tile t0+2 (buf0) complete
    SBAR();
  }

  // LDS-staged coalesced epilogue (32x32 C-layout: col=lo, row=(r&3)+8*(r>>2)+4*hi)
  if (EPI != 4) {
    u16* dst = Co; long colBase = bCol; long strideW = N;
    if (EPI == 6) {
      strideW = 1024;
      if (bCol >= 1024) { dst = Co2; colBase = bCol - 1024; }
    }
    u16* lds16 = (u16*)ldsc;
#pragma unroll
    for (int Qr = 0; Qr < 2; ++Qr)
#pragma unroll
      for (int Qc = 0; Qc < 2; ++Qc) {
        const int colL = Qc * 128 + wc * 32 + lo;
        const float bs = bias ? bias[bCol + colL] : 0.f;
#pragma unroll
        for (int m = 0; m < 2; ++m)
#pragma unroll
          for (int r = 0; r < 16; ++r) {
            const int rowL = Qr * 128 + wr * 64 + m * 32 + (r & 3) + 8 * (r >> 2) + 4 * hi;
            float v = acc[Qr][Qc][m][r] + bs;
            if (EPI == 3) v = fmaxf(v, 0.f);
            lds16[rowL * 256 + colL] = f2bf(v);
          }
      }
    __syncthreads();
    const int rB = tid >> 5, cL = (tid & 31) * 8;
#pragma unroll
    for (int it = 0; it < 16; ++it) {
      const int rL = it * 16 + rB;
      const long gr = bRow + rL;
      u16x8 sv = *(const u16x8*)(lds16 + rL * 256 + cL);
      if (EPI == 5) {
        u16x8 ad = *(const u16x8*)(addend + gr * (long)N + bCol + cL);
#pragma unroll
        for (int j = 0; j < 8; ++j) sv[j] = f2bf(bf2f(sv[j]) + bf2f(ad[j]));
      }
      *(u16x8*)(dst + gr * strideW + colBase + cL) = sv;
    }
  } else {
    float* ldsf = (float*)ldsc;
#pragma unroll
    for (int p = 0; p < 2; ++p) {
#pragma unroll
      for (int Qc = 0; Qc < 2; ++Qc) {
        const int colL = Qc * 128 + wc * 32 + lo;
        const float bs = bias ? bias[bCol + colL] : 0.f;
#pragma unroll
        for (int m = 0; m < 2; ++m)
#pragma unroll
          for (int r = 0; r < 16; ++r) {
            const int rowL = wr * 64 + m * 32 + (r & 3) + 8 * (r >> 2) + 4 * hi;
            ldsf[rowL * 256 + colL] = acc[p][Qc][m][r] + bs;
          }
      }
      __syncthreads();
      const int c4 = (tid & 63) * 4, rB = tid >> 6;
#pragma unroll
      for (int it = 0; it < 16; ++it) {
        const int rL = it * 8 + rB;
        const long gr = bRow + p * 128 + rL;
        float4 fv = *(const float4*)(ldsf + rL * 256 + c4);
        *(float4*)(Cf + gr * (long)N + bCol + c4) = fv;
      }
      __syncthreads();
    }
  }
}

// ---------------- attention, 4 heads per 256-thread block; o may alias q ----------------
__global__ __launch_bounds__(256) void attn4_kernel(const u16* q,
                                                    const u16* __restrict__ k,
                                                    const u16* __restrict__ v,
                                                    u16* o) {
  const int tid = threadIdx.x;
  const int wid = tid >> 6, l = tid & 63;
  const int bh = blockIdx.x * 4 + wid;
  const int b = bh >> 3, hd = bh & 7;
  const long base = (long)b * 32 * 1024 + hd * 128;
  const int lo = l & 31, hi = l >> 5;
  __shared__ u16 P[4][32 * 36];
  __shared__ u16 Vt[4][128 * 36];
  u16* Pw = P[wid];
  u16* Vw = Vt[wid];

#pragma unroll
  for (int i = 0; i < 8; ++i) {
    int idx = i * 64 + l;
    int tok = idx >> 4, d0 = (idx & 15) * 8;
    const u16* src = v + base + (long)tok * 1024 + d0;
    ushort4 a0 = *(const ushort4*)src;
    ushort4 a1 = *(const ushort4*)(src + 4);
    u16 vals[8] = {a0.x, a0.y, a0.z, a0.w, a1.x, a1.y, a1.z, a1.w};
#pragma unroll
    for (int j = 0; j < 8; ++j) Vw[(d0 + j) * 36 + tok] = vals[j];
  }

  f32x16 st;
#pragma unroll
  for (int r = 0; r < 16; ++r) st[r] = 0.f;
#pragma unroll
  for (int kb = 0; kb < 8; ++kb) {
    bf16x8 kf = *(const bf16x8*)(k + base + (long)lo * 1024 + kb * 16 + hi * 8);
    bf16x8 qf = *(const bf16x8*)(q + base + (long)lo * 1024 + kb * 16 + hi * 8);
    st = __builtin_amdgcn_mfma_f32_32x32x16_bf16(kf, qf, st, 0, 0, 0);
  }
  float mx = -1e30f;
#pragma unroll
  for (int r = 0; r < 16; ++r) { st[r] *= 0.08838834764831845f; mx = fmaxf(mx, st[r]); }
  mx = fmaxf(mx, __shfl_xor(mx, 32));
  float p[16], sum = 0.f;
#pragma unroll
  for (int r = 0; r < 16; ++r) { p[r] = __expf(st[r] - mx); sum += p[r]; }
  sum += __shfl_xor(sum, 32);
  const float inv = 1.f / sum;
#pragma unroll
  for (int r = 0; r < 16; ++r) {
    int kt = (r & 3) + 8 * (r >> 2) + 4 * hi;
    Pw[lo * 36 + kt] = f2bf(p[r] * inv);
  }
  __syncthreads();

#pragma unroll
  for (int nb = 0; nb < 4; ++nb) {
    f32x16 oa;
#pragma unroll
    for (int r = 0; r < 16; ++r) oa[r] = 0.f;
#pragma unroll
    for (int ks = 0; ks < 2; ++ks) {
      union { bf16x8 v8; ushort4 h[2]; } pa, vb;
      pa.h[0] = *(const ushort4*)&Pw[lo * 36 + ks * 16 + hi * 8];
      pa.h[1] = *(const ushort4*)&Pw[lo * 36 + ks * 16 + hi * 8 + 4];
      vb.h[0] = *(const ushort4*)&Vw[(nb * 32 + lo) * 36 + ks * 16 + hi * 8];
      vb.h[1] = *(const ushort4*)&Vw[(nb * 32 + lo) * 36 + ks * 16 + hi * 8 + 4];
      oa = __builtin_amdgcn_mfma_f32_32x32x16_bf16(pa.v8, vb.v8, oa, 0, 0, 0);
    }
#pragma unroll
    for (int r = 0; r < 16; ++r) {
      int qrow = (r & 3) + 8 * (r >> 2) + 4 * hi;
      o[base + (long)qrow * 1024 + nb * 32 + lo] = f2bf(oa[r]);
    }
  }
}

// ---------------- launch ----------------
extern "C" void kernel_launch(void* const* d_in, const int* in_sizes, int n_in,
                              void* d_out, int out_size, void* d_ws, size_t ws_size,
                              hipStream_t stream) {
  const float* state = (const float*)d_in[0];  const float* cond  = (const float*)d_in[1];
  const float* ew1 = (const float*)d_in[2];    const float* eb1 = (const float*)d_in[3];
  const float* eg1 = (const float*)d_in[4];    const float* ebt1 = (const float*)d_in[5];
  const float* ew2 = (const float*)d_in[6];    const float* eb2 = (const float*)d_in[7];
  const float* eg2 = (const float*)d_in[8];    const float* ebt2 = (const float*)d_in[9];
  const float* rw = (const float*)d_in[10];    const float* rb = (const float*)d_in[11];
  const float* fw1 = (const float*)d_in[12];   const float* fb1 = (const float*)d_in[13];
  const float* fw2 = (const float*)d_in[14];   const float* fb2 = (const float*)d_in[15];
  const float* lnq_g = (const float*)d_in[16]; const float* lnq_b = (const float*)d_in[17];
  const float* wq = (const float*)d_in[18];    const float* wk = (const float*)d_in[19];
  const float* wv = (const float*)d_in[20];    const float* wo = (const float*)d_in[21];
  const float* cn_g = (const float*)d_in[22];  const float* cn_b = (const float*)d_in[23];
  const float* hw1 = (const float*)d_in[24];   const float* hb1 = (const float*)d_in[25];
  const float* hw2 = (const float*)d_in[26];   const float* hb2 = (const float*)d_in[27];

  const size_t MB128 = 134217728ULL;
  const size_t WT_BYTES = 17367040ULL;
  const size_t FH_BYTES = 16777216ULL;
  char* ws = (char*)d_ws;
  u16* OUTu = (u16*)d_out;
  float* OUTf = (float*)d_out;

  (void)hipFuncSetAttribute((const void*)gemm256<0>, hipFuncAttributeMaxDynamicSharedMemorySize, 131072);
  (void)hipFuncSetAttribute((const void*)gemm256<3>, hipFuncAttributeMaxDynamicSharedMemorySize, 131072);
  (void)hipFuncSetAttribute((const void*)gemm256<4>, hipFuncAttributeMaxDynamicSharedMemorySize, 131072);
  (void)hipFuncSetAttribute((const void*)gemm256<5>, hipFuncAttributeMaxDynamicSharedMemorySize, 131072);
  (void)hipFuncSetAttribute((const void*)gemm256<6>, hipFuncAttributeMaxDynamicSharedMemorySize, 131072);
  (void)hipFuncSetAttribute((const void*)film_qin,   hipFuncAttributeMaxDynamicSharedMemorySize, 73984);

  u16* wt = nullptr;
  bool planA = false;
  int R = 0;
  if (ws_size >= 3 * MB128 + FH_BYTES + WT_BYTES) {
    planA = true;
    wt = (u16*)(ws + 3 * MB128 + FH_BYTES);
  } else {
    for (int r = 8192; r >= 1024; r >>= 1) {
      size_t need = 2 * MB128 + (size_t)r * 8448ULL + WT_BYTES;
      if (ws_size >= need) { R = r; wt = (u16*)(ws + 2 * MB128 + (size_t)r * 8448ULL); break; }
    }
    if (!R) return;
  }

  u16* ew1T = wt + 0;        u16* rwT  = wt + 786432;  u16* ew2T = wt + 1572864;
  u16* fw1T = wt + 2621440;  u16* fw2T = wt + 2654208;
  u16* wqT  = wt + 2916352;  u16* wkT  = wt + 3964928; u16* wvT  = wt + 5013504;
  u16* woT  = wt + 6062080;  u16* hw1T = wt + 7110656; u16* hw2T = wt + 8159232;

  if (planA) {
    u16* S1 = (u16*)ws;
    u16* S2 = (u16*)(ws + MB128);
    u16* S3 = (u16*)(ws + 2 * MB128);
    u16* FH = (u16*)(ws + 3 * MB128);

    WSrc src;
    src.p[0] = ew1; src.p[1] = rw;  src.p[2] = ew2; src.p[3] = fw1; src.p[4] = fw2;
    src.p[5] = wq;  src.p[6] = wk;  src.p[7] = wv;  src.p[8] = wo;  src.p[9] = hw1;
    src.p[10] = hw2;
    init_kernel<<<57632, 256, 0, stream>>>(src, wt, state, cond, S1);

    gemm_bt<1><<<dim3(512, 1), 256, 0, stream>>>(S1 + 512, fw1T, fb1, nullptr, FH, nullptr, 128, 256, 768);
    gemm256<0><<<1024, 512, 131072, stream>>>(S1, ew1T, eb1, nullptr, S2, nullptr, nullptr, 1024, 768, 768, 2);   // y1=S2
    ln_relu_w<<<16384, 256, 0, stream>>>(S2, eg1, ebt1, S2);                                   // h1=S2
    gemm256<0><<<1024, 512, 131072, stream>>>(S2, ew2T, eb2, nullptr, S3, nullptr, nullptr, 1024, 1024, 1024, 2); // y2=S3
    ln_relu_w<<<16384, 256, 0, stream>>>(S3, eg2, ebt2, S3);                                   // hbf=S3
    film_qin<<<2048, 256, 73984, stream>>>(S3, FH, fw2T, fb2, lnq_g, lnq_b, OUTu);             // qin=OUT
    gemm256<0><<<1024, 512, 131072, stream>>>(OUTu, wqT, nullptr, nullptr, S1, nullptr, nullptr, 1024, 1024, 1024, 2); // q=S1
    gemm256<6><<<2048, 512, 131072, stream>>>(S3, wkT, nullptr, nullptr, S2, OUTu, nullptr, 2048, 1024, 1024, 3);      // k=S2, v=OUT
    attn4_kernel<<<4096, 256, 0, stream>>>(S1, S2, OUTu, S1);                                  // o=S1
    prep_kernel<<<49152, 256, 0, stream>>>(state, cond, S2);                                   // xb2=S2
    gemm256<0><<<1024, 512, 131072, stream>>>(S2, rwT, rb, nullptr, OUTu, nullptr, nullptr, 1024, 768, 768, 2);   // res=OUT
    gemm256<5><<<1024, 512, 131072, stream>>>(S1, woT, nullptr, OUTu, OUTu, nullptr, nullptr, 1024, 1024, 1024, 2); // o2=OUT
    h2_w<<<16384, 256, 0, stream>>>(S3, OUTu, cn_g, cn_b, S1);                                 // h2=S1
    gemm256<3><<<1024, 512, 131072, stream>>>(S1, hw1T, hb1, nullptr, S2, nullptr, nullptr, 1024, 1024, 1024, 2); // mh=S2
    gemm256<4><<<512, 512, 131072, stream>>>(S2, hw2T, hb2, nullptr, nullptr, nullptr, OUTf, 512, 1024, 1024, 1);
    return;
  }

  // ---- Plan C: chunked fallback ----
  transpose_cvt<<<dim3(32, 24), 256, 0, stream>>>(ew1, ew1T, 768, 1024);
  transpose_cvt<<<dim3(32, 24), 256, 0, stream>>>(rw,  rwT,  768, 1024);
  transpose_cvt<<<dim3(32, 32), 256, 0, stream>>>(ew2, ew2T, 1024, 1024);
  transpose_cvt<<<dim3(4, 8),   256, 0, stream>>>(fw1, fw1T, 256, 128);
  transpose_cvt<<<dim3(64, 4),  256, 0, stream>>>(fw2, fw2T, 128, 2048);
  transpose_cvt<<<dim3(32, 32), 256, 0, stream>>>(wq, wqT, 1024, 1024);
  transpose_cvt<<<dim3(32, 32), 256, 0, stream>>>(wk, wkT, 1024, 1024);
  transpose_cvt<<<dim3(32, 32), 256, 0, stream>>>(wv, wvT, 1024, 1024);
  transpose_cvt<<<dim3(32, 32), 256, 0, stream>>>(wo, woT, 1024, 1024);
  transpose_cvt<<<dim3(32, 32), 256, 0, stream>>>(hw1, hw1T, 1024, 1024);
  transpose_cvt<<<dim3(16, 32), 256, 0, stream>>>(hw2, hw2T, 1024, 512);

  u16* F1 = (u16*)ws;
  u16* F2 = (u16*)(ws + MB128);
  char* g = ws + 2 * MB128;
  u16* G0 = (u16*)g;
  u16* G1 = (u16*)(g + (size_t)R * 2048);
  u16* G2 = (u16*)(g + (size_t)R * 4096);
  u16* G3 = (u16*)(g + (size_t)R * 4096 + (size_t)R * 256);
  u16* G4 = (u16*)(g + (size_t)R * 6144 + (size_t)R * 256);
  const int GX = R / 128, CH = 65536 / R;

  for (int c = 0; c < CH; ++c) {
    const long r0 = (long)c * R;
    prep_kernel<<<R * 3 / 4, 256, 0, stream>>>(state + r0 * 512, cond + r0 * 256, G0);
    gemm_bt<1><<<dim3(GX, 1), 256, 0, stream>>>(G0 + 512, fw1T, fb1, nullptr, G2, nullptr, 128, 256, 768);
    gemm_bt<0><<<dim3(GX, 8), 256, 0, stream>>>(G0, ew1T, eb1, nullptr, G1, nullptr, 1024, 768, 768);
    gemm_bt<0><<<dim3(GX, 8), 256, 0, stream>>>(G0, rwT,  rb,  nullptr, F2 + r0 * 1024, nullptr, 1024, 768, 768);
    ln_relu_w<<<R / 4, 256, 0, stream>>>(G1, eg1, ebt1, G3);
    gemm_bt<0><<<dim3(GX, 8), 256, 0, stream>>>(G3, ew2T, eb2, nullptr, G0, nullptr, 1024, 1024, 1024);
    ln_relu_w<<<R / 4, 256, 0, stream>>>(G0, eg2, ebt2, F1 + r0 * 1024);
    gemm_bt<2><<<dim3(GX, 8), 256, 0, stream>>>(G2, fw2T, fb2, nullptr, G3, nullptr, 1024, 128, 128);
    gemm_bt<6><<<dim3(GX, 8), 256, 0, stream>>>(G2, fw2T + 131072, fb2 + 1024, nullptr, G1, nullptr, 1024, 128, 128);
    qin_sep_kernel<<<R, 256, 0, stream>>>(F1 + r0 * 1024, G3, G1, lnq_g, lnq_b, G3);
    gemm_bt<0><<<dim3(GX, 8), 256, 0, stream>>>(G3, wqT, nullptr, nullptr, G0, nullptr, 1024, 1024, 1024);
    gemm_bt<0><<<dim3(GX, 8), 256, 0, stream>>>(F1 + r0 * 1024, wkT, nullptr, nullptr, G1, nullptr, 1024, 1024, 1024);
    gemm_bt<0><<<dim3(GX, 8), 256, 0, stream>>>(F1 + r0 * 1024, wvT, nullptr, nullptr, G4, nullptr, 1024, 1024, 1024);
    attn4_kernel<<<R / 16, 256, 0, stream>>>(G0, G1, G4, G0);
    gemm_bt<5><<<dim3(GX, 8), 256, 0, stream>>>(G0, woT, nullptr, F2 + r0 * 1024, F2 + r0 * 1024, nullptr, 1024, 1024, 1024);
  }
  h2_w<<<16384, 256, 0, stream>>>(F1, F2, cn_g, cn_b, OUTu);
  gemm_bt<3><<<dim3(512, 8), 256, 0, stream>>>(OUTu, hw1T, hb1, nullptr, F1, nullptr, 1024, 1024, 1024);
  gemm_bt<4><<<dim3(512, 4), 256, 0, stream>>>(F1, hw2T, hb2, nullptr, nullptr, OUTf, 512, 1024, 1024);
}

// Round 15
// 1941.482 us; speedup vs baseline: 1.0548x; 1.0548x over previous
//
#include <hip/hip_runtime.h>
#include <hip/hip_bf16.h>

typedef unsigned short u16;
typedef short bf16x8 __attribute__((ext_vector_type(8)));
typedef u16 u16x8 __attribute__((ext_vector_type(8)));
typedef float f32x4 __attribute__((ext_vector_type(4)));
typedef float f32x16 __attribute__((ext_vector_type(16)));

#define DEV __device__ __forceinline__

DEV u16 f2bf(float f) {
  union { float f; unsigned u; } a; a.f = f;
  unsigned r = a.u + 0x7FFFu + ((a.u >> 16) & 1u);
  return (u16)(r >> 16);
}
DEV float bf2f(u16 u) {
  union { unsigned u; float f; } a; a.u = ((unsigned)u) << 16; return a.f;
}
DEV float ftanh(float v) {               // exp-based tanh; saturates correctly
  float e = __expf(2.f * v);
  return 1.f - 2.f / (e + 1.f);
}
DEV void async16(const void* g, void* l) {
  __builtin_amdgcn_global_load_lds(
      (const __attribute__((address_space(1))) unsigned int*)g,
      (__attribute__((address_space(3))) unsigned int*)l, 16, 0, 0);
}

#define SBAR() asm volatile("s_barrier" ::: "memory")
#define WAITV(n) asm volatile("s_waitcnt vmcnt(" #n ")" ::: "memory")

// ---------------- transpose + cvt: fp32 [K][N] -> bf16 [N][K] (Plan C) ----------------
__global__ __launch_bounds__(256) void transpose_cvt(const float* __restrict__ in,
                                                     u16* __restrict__ out, int K, int N) {
  __shared__ float tile[32][33];
  const int kt = blockIdx.y * 32, nt = blockIdx.x * 32;
  const int tx = threadIdx.x & 31, ty = threadIdx.x >> 5;
#pragma unroll
  for (int i = 0; i < 32; i += 8) {
    int k = kt + ty + i, n = nt + tx;
    tile[ty + i][tx] = (k < K && n < N) ? in[(long)k * N + n] : 0.f;
  }
  __syncthreads();
#pragma unroll
  for (int i = 0; i < 32; i += 8) {
    int n = nt + ty + i, k = kt + tx;
    if (n < N && k < K) out[(long)n * K + k] = f2bf(tile[tx][ty + i]);
  }
}

// ---------------- prep: concat + clip -> bf16 [R][768] ----------------
__global__ __launch_bounds__(256) void prep_kernel(const float* __restrict__ state,
                                                   const float* __restrict__ cond,
                                                   u16* __restrict__ xb) {
  int idx = blockIdx.x * 256 + threadIdx.x;
  int t = idx / 192, c4 = idx - t * 192;
  float4 v;
  if (c4 < 128) v = ((const float4*)state)[(long)t * 128 + c4];
  else          v = ((const float4*)cond)[(long)t * 64 + (c4 - 128)];
  ushort4 o;
  o.x = f2bf(fminf(fmaxf(v.x, -16.f), 16.f));
  o.y = f2bf(fminf(fmaxf(v.y, -16.f), 16.f));
  o.z = f2bf(fminf(fmaxf(v.z, -16.f), 16.f));
  o.w = f2bf(fminf(fmaxf(v.w, -16.f), 16.f));
  *(ushort4*)(xb + (long)t * 768 + c4 * 4) = o;
}

// ---------------- merged init: 11 weight transposes + prep in ONE launch ----------------
struct WSrc { const float* p[11]; };
__global__ __launch_bounds__(256) void init_kernel(WSrc src, u16* __restrict__ wt,
                                                   const float* __restrict__ state,
                                                   const float* __restrict__ cond,
                                                   u16* __restrict__ xb) {
  __shared__ float tile[32][33];
  const int b = blockIdx.x;
  if (b >= 8480) {  // prep job
    int idx = (b - 8480) * 256 + threadIdx.x;
    int t = idx / 192, c4 = idx - t * 192;
    float4 v;
    if (c4 < 128) v = ((const float4*)state)[(long)t * 128 + c4];
    else          v = ((const float4*)cond)[(long)t * 64 + (c4 - 128)];
    ushort4 o;
    o.x = f2bf(fminf(fmaxf(v.x, -16.f), 16.f));
    o.y = f2bf(fminf(fmaxf(v.y, -16.f), 16.f));
    o.z = f2bf(fminf(fmaxf(v.z, -16.f), 16.f));
    o.w = f2bf(fminf(fmaxf(v.w, -16.f), 16.f));
    *(ushort4*)(xb + (long)t * 768 + c4 * 4) = o;
    return;
  }
  int job, base, K, N, X;
  long off;
  if      (b < 768)  { job = 0;  base = 0;    K = 768;  N = 1024; X = 32; off = 0; }
  else if (b < 1536) { job = 1;  base = 768;  K = 768;  N = 1024; X = 32; off = 786432; }
  else if (b < 2560) { job = 2;  base = 1536; K = 1024; N = 1024; X = 32; off = 1572864; }
  else if (b < 2592) { job = 3;  base = 2560; K = 256;  N = 128;  X = 4;  off = 2621440; }
  else if (b < 2848) { job = 4;  base = 2592; K = 128;  N = 2048; X = 64; off = 2654208; }
  else if (b < 3872) { job = 5;  base = 2848; K = 1024; N = 1024; X = 32; off = 2916352; }
  else if (b < 4896) { job = 6;  base = 3872; K = 1024; N = 1024; X = 32; off = 3964928; }
  else if (b < 5920) { job = 7;  base = 4896; K = 1024; N = 1024; X = 32; off = 5013504; }
  else if (b < 6944) { job = 8;  base = 5920; K = 1024; N = 1024; X = 32; off = 6062080; }
  else if (b < 7968) { job = 9;  base = 6944; K = 1024; N = 1024; X = 32; off = 7110656; }
  else               { job = 10; base = 7968; K = 1024; N = 512;  X = 16; off = 8159232; }
  const float* in = src.p[job];
  u16* out = wt + off;
  const int lb = b - base;
  const int kt = (lb / X) * 32, nt = (lb % X) * 32;
  const int tx = threadIdx.x & 31, ty = threadIdx.x >> 5;
#pragma unroll
  for (int i = 0; i < 32; i += 8) {
    int k = kt + ty + i, n = nt + tx;
    tile[ty + i][tx] = (k < K && n < N) ? in[(long)k * N + n] : 0.f;
  }
  __syncthreads();
#pragma unroll
  for (int i = 0; i < 32; i += 8) {
    int n = nt + ty + i, k = kt + tx;
    if (n < N && k < K) out[(long)n * K + k] = f2bf(tile[tx][ty + i]);
  }
}

// ---------------- per-wave reduce ----------------
DEV void wreduce2(float& s, float& q) {
#pragma unroll
  for (int off = 32; off; off >>= 1) { s += __shfl_xor(s, off); q += __shfl_xor(q, off); }
}

// ---------------- per-wave LN+ReLU: 1 wave = 1 row; in-place safe ----------------
__global__ __launch_bounds__(256) void ln_relu_w(const u16* in,
                                                 const float* __restrict__ g,
                                                 const float* __restrict__ bt,
                                                 u16* out) {
  const int wid = threadIdx.x >> 6, lane = threadIdx.x & 63;
  const long row = (long)blockIdx.x * 4 + wid;
  const u16* ip = in + row * 1024 + lane * 16;
  u16x8 v0 = *(const u16x8*)ip;
  u16x8 v1 = *(const u16x8*)(ip + 8);
  float x[16];
#pragma unroll
  for (int j = 0; j < 8; ++j) { x[j] = bf2f(v0[j]); x[8 + j] = bf2f(v1[j]); }
  float s = 0.f, q = 0.f;
#pragma unroll
  for (int j = 0; j < 16; ++j) { s += x[j]; q += x[j] * x[j]; }
  wreduce2(s, q);
  float mean = s * (1.f / 1024.f);
  float var  = q * (1.f / 1024.f) - mean * mean;
  float rs   = rsqrtf(var + 1e-5f);
  const int c0 = lane * 16;
  float4 g0 = *(const float4*)(g + c0),      g1 = *(const float4*)(g + c0 + 4);
  float4 g2 = *(const float4*)(g + c0 + 8),  g3 = *(const float4*)(g + c0 + 12);
  float4 b0 = *(const float4*)(bt + c0),     b1 = *(const float4*)(bt + c0 + 4);
  float4 b2 = *(const float4*)(bt + c0 + 8), b3 = *(const float4*)(bt + c0 + 12);
  float ga[16] = {g0.x,g0.y,g0.z,g0.w, g1.x,g1.y,g1.z,g1.w, g2.x,g2.y,g2.z,g2.w, g3.x,g3.y,g3.z,g3.w};
  float ba[16] = {b0.x,b0.y,b0.z,b0.w, b1.x,b1.y,b1.z,b1.w, b2.x,b2.y,b2.z,b2.w, b3.x,b3.y,b3.z,b3.w};
  u16x8 o0, o1;
#pragma unroll
  for (int j = 0; j < 8; ++j) {
    o0[j] = f2bf(fmaxf((x[j] - mean) * rs * ga[j] + ba[j], 0.f));
    o1[j] = f2bf(fmaxf((x[8 + j] - mean) * rs * ga[8 + j] + ba[8 + j], 0.f));
  }
  u16* op = out + row * 1024 + lane * 16;
  *(u16x8*)op = o0;
  *(u16x8*)(op + 8) = o1;
}

// ---------------- per-wave h2 = LN(h + o2) ----------------
__global__ __launch_bounds__(256) void h2_w(const u16* __restrict__ h,
                                            const u16* o2,
                                            const float* __restrict__ g,
                                            const float* __restrict__ bt,
                                            u16* out) {
  const int wid = threadIdx.x >> 6, lane = threadIdx.x & 63;
  const long row = (long)blockIdx.x * 4 + wid;
  const u16* hp = h + row * 1024 + lane * 16;
  const u16* op2 = o2 + row * 1024 + lane * 16;
  u16x8 a0 = *(const u16x8*)hp,  a1 = *(const u16x8*)(hp + 8);
  u16x8 c0v = *(const u16x8*)op2, c1v = *(const u16x8*)(op2 + 8);
  float x[16];
#pragma unroll
  for (int j = 0; j < 8; ++j) {
    x[j]     = bf2f(a0[j]) + bf2f(c0v[j]);
    x[8 + j] = bf2f(a1[j]) + bf2f(c1v[j]);
  }
  float s = 0.f, q = 0.f;
#pragma unroll
  for (int j = 0; j < 16; ++j) { s += x[j]; q += x[j] * x[j]; }
  wreduce2(s, q);
  float mean = s * (1.f / 1024.f);
  float var  = q * (1.f / 1024.f) - mean * mean;
  float rs   = rsqrtf(var + 1e-5f);
  const int cc = lane * 16;
  u16x8 o0, o1;
#pragma unroll
  for (int j = 0; j < 8; ++j) {
    o0[j] = f2bf((x[j] - mean) * rs * g[cc + j] + bt[cc + j]);
    o1[j] = f2bf((x[8 + j] - mean) * rs * g[cc + 8 + j] + bt[cc + 8 + j]);
  }
  u16* op = out + row * 1024 + lane * 16;
  *(u16x8*)op = o0;
  *(u16x8*)(op + 8) = o1;
}

// ---------------- qin with separate gain/bias (Plan C; qout may alias gain) ----------------
__global__ __launch_bounds__(256) void qin_sep_kernel(const u16* __restrict__ h,
                                                      const u16* gain, const u16* bias,
                                                      const float* __restrict__ lg,
                                                      const float* __restrict__ lbt,
                                                      u16* qout) {
  __shared__ float sh[8];
  const long row = blockIdx.x;
  const int tid = threadIdx.x;
  ushort4 hv = *(const ushort4*)(h + row * 1024 + tid * 4);
  float x[4] = {bf2f(hv.x), bf2f(hv.y), bf2f(hv.z), bf2f(hv.w)};
  float s = x[0] + x[1] + x[2] + x[3];
  float q = x[0]*x[0] + x[1]*x[1] + x[2]*x[2] + x[3]*x[3];
#pragma unroll
  for (int off = 32; off; off >>= 1) { s += __shfl_xor(s, off); q += __shfl_xor(q, off); }
  const int w = tid >> 6;
  if ((tid & 63) == 0) { sh[w] = s; sh[4 + w] = q; }
  __syncthreads();
  s = sh[0] + sh[1] + sh[2] + sh[3];
  q = sh[4] + sh[5] + sh[6] + sh[7];
  float mean = s * (1.f / 1024.f);
  float var  = q * (1.f / 1024.f) - mean * mean;
  float rs   = rsqrtf(var + 1e-5f);
  ushort4 gv = *(const ushort4*)(gain + row * 1024 + tid * 4);
  ushort4 bv = *(const ushort4*)(bias + row * 1024 + tid * 4);
  const u16* gp = (const u16*)&gv;
  const u16* bp = (const u16*)&bv;
  ushort4 ov; u16* op = (u16*)&ov;
#pragma unroll
  for (int j = 0; j < 4; ++j) {
    int c = tid * 4 + j;
    float y = (x[j] - mean) * rs * lg[c] + lbt[c];
    op[j] = f2bf(y * bf2f(gp[j]) + bf2f(bp[j]));
  }
  *(ushort4*)(qout + row * 1024 + tid * 4) = ov;
}

// ============ fused FiLM + qin ============
__global__ __launch_bounds__(256) void film_qin(const u16* __restrict__ hbf,
                                                const u16* __restrict__ fh,
                                                const u16* __restrict__ fw2T,
                                                const float* __restrict__ fb2,
                                                const float* __restrict__ lg,
                                                const float* __restrict__ lbt,
                                                u16* __restrict__ qout) {
  extern __shared__ char lds[];
  u16* H = (u16*)lds;                 // [32][1024]
  char* Afh = lds + 65536;            // 8 KB swizzled [32][128] bf16
  float* sLN = (float*)(lds + 73728); // [32][2]
  const int tid = threadIdx.x;
  const int wid = tid >> 6, lane = tid & 63;
  const int fr = lane & 15, fq = lane >> 4;
  const long rows0 = (long)blockIdx.x * 32;

  {
    const int row = tid >> 3;
    const int inner = (tid & 7) * 32;
    const u16* src = fh + (rows0 + row) * 128 + (tid & 7) * 16;
    u16x8 f0 = *(const u16x8*)src;
    u16x8 f1 = *(const u16x8*)(src + 8);
    *(u16x8*)(Afh + row * 256 + ((inner)      ^ ((row & 7) << 4))) = f0;
    *(u16x8*)(Afh + row * 256 + ((inner + 16) ^ ((row & 7) << 4))) = f1;
  }

#pragma unroll
  for (int i = 0; i < 8; ++i) {
    const int row = i * 4 + wid;
    const u16* src = hbf + (rows0 + row) * 1024 + lane * 16;
    u16x8 v0 = *(const u16x8*)src;
    u16x8 v1 = *(const u16x8*)(src + 8);
    *(u16x8*)(H + row * 1024 + lane * 16) = v0;
    *(u16x8*)(H + row * 1024 + lane * 16 + 8) = v1;
    float s = 0.f, q = 0.f;
#pragma unroll
    for (int j = 0; j < 8; ++j) {
      float x0 = bf2f(v0[j]), x1 = bf2f(v1[j]);
      s += x0 + x1; q += x0 * x0 + x1 * x1;
    }
    wreduce2(s, q);
    if (lane == 0) {
      float mean = s * (1.f / 1024.f);
      float var  = q * (1.f / 1024.f) - mean * mean;
      sLN[row * 2] = mean;
      sLN[row * 2 + 1] = rsqrtf(var + 1e-5f);
    }
  }
  __syncthreads();

  const int cbase = wid * 256;
#pragma unroll 1
  for (int c8 = 0; c8 < 16; ++c8) {
    const int c = cbase + c8 * 16;
    const int col = c + fr;
    f32x4 ag[2] = {{0.f,0.f,0.f,0.f},{0.f,0.f,0.f,0.f}};
    f32x4 ab[2] = {{0.f,0.f,0.f,0.f},{0.f,0.f,0.f,0.f}};
#pragma unroll
    for (int ks = 0; ks < 4; ++ks) {
      bf16x8 bg = *(const bf16x8*)(fw2T + (long)col * 128 + ks * 32 + fq * 8);
      bf16x8 bb = *(const bf16x8*)(fw2T + (long)(1024 + col) * 128 + ks * 32 + fq * 8);
#pragma unroll
      for (int t = 0; t < 2; ++t) {
        const int row = t * 16 + fr;
        bf16x8 av = *(const bf16x8*)(Afh + row * 256 + ((ks * 64 + fq * 16) ^ ((fr & 7) << 4)));
        ag[t] = __builtin_amdgcn_mfma_f32_16x16x32_bf16(av, bg, ag[t], 0, 0, 0);
        ab[t] = __builtin_amdgcn_mfma_f32_16x16x32_bf16(av, bb, ab[t], 0, 0, 0);
      }
    }
    const float fg = fb2[col], fb = fb2[1024 + col];
    const float lgc = lg[col], lbc = lbt[col];
#pragma unroll
    for (int t = 0; t < 2; ++t)
#pragma unroll
      for (int r = 0; r < 4; ++r) {
        const int row = t * 16 + fq * 4 + r;
        float gv = 1.f + 0.5f * ftanh(ag[t][r] + fg);
        float bv = 0.5f * ftanh(ab[t][r] + fb);
        float x = bf2f(H[row * 1024 + col]);
        float y = (x - sLN[row * 2]) * sLN[row * 2 + 1] * lgc + lbc;
        H[row * 1024 + col] = f2bf(y * gv + bv);
      }
  }
  __syncthreads();

#pragma unroll
  for (int i = 0; i < 8; ++i) {
    const int row = i * 4 + wid;
    u16* dst = qout + (rows0 + row) * 1024 + lane * 16;
    *(u16x8*)dst = *(const u16x8*)(H + row * 1024 + lane * 16);
    *(u16x8*)(dst + 8) = *(const u16x8*)(H + row * 1024 + lane * 16 + 8);
  }
}

// ============ 128x128 GEMM (FiLM1 + Plan C) ============
template <int EPI>
__global__ __launch_bounds__(256) void gemm_bt(const u16* __restrict__ A,
                                               const u16* __restrict__ Bt,
                                               const float* __restrict__ bias,
                                               const u16* addend,
                                               u16* Co, float* Cf,
                                               int N, int K, int lda) {
  __shared__ u16 As[128 * 64];
  __shared__ u16 Bs[128 * 64];
  const int tid = threadIdx.x;
  const int w = tid >> 6, l = tid & 63;
  const int wr = w >> 1, wc = w & 1;
  const long bRow = (long)blockIdx.x * 128;
  const long bCol = (long)blockIdx.y * 128;

  f32x4 acc[4][4];
#pragma unroll
  for (int mi = 0; mi < 4; ++mi)
#pragma unroll
    for (int ni = 0; ni < 4; ++ni) acc[mi][ni] = (f32x4){0.f, 0.f, 0.f, 0.f};

  const int arow = l >> 3;
  const int acol = (l & 7) * 8;
  const u16* gA = A + (bRow + w * 8 + arow) * (long)lda + acol;
  const u16* gB = Bt + (bCol + w * 8 + arow) * (long)K + acol;

  const int fr = l & 15;
  const int fks = (l >> 4) * 8;

  for (int kt = 0; kt < K; kt += 64) {
#pragma unroll
    for (int i = 0; i < 4; ++i) {
      async16(gA + (long)i * 32 * lda + kt, As + (i * 32 + w * 8) * 64);
      async16(gB + (long)i * 32 * K   + kt, Bs + (i * 32 + w * 8) * 64);
    }
    __syncthreads();
#pragma unroll
    for (int kk = 0; kk < 2; ++kk) {
      const int ko = kk * 32 + fks;
      bf16x8 af[4], bff[4];
#pragma unroll
      for (int mi = 0; mi < 4; ++mi)
        af[mi] = *(const bf16x8*)(As + (wr * 64 + mi * 16 + fr) * 64 + ko);
#pragma unroll
      for (int ni = 0; ni < 4; ++ni)
        bff[ni] = *(const bf16x8*)(Bs + (wc * 64 + ni * 16 + fr) * 64 + ko);
#pragma unroll
      for (int mi = 0; mi < 4; ++mi)
#pragma unroll
        for (int ni = 0; ni < 4; ++ni)
          acc[mi][ni] = __builtin_amdgcn_mfma_f32_16x16x32_bf16(af[mi], bff[ni], acc[mi][ni], 0, 0, 0);
    }
    __syncthreads();
  }

  const int fq = l >> 4;
#pragma unroll
  for (int ni = 0; ni < 4; ++ni) {
    const long col = bCol + wc * 64 + ni * 16 + fr;
    const float bs = bias ? bias[col] : 0.f;
#pragma unroll
    for (int mi = 0; mi < 4; ++mi) {
#pragma unroll
      for (int r = 0; r < 4; ++r) {
        const long row = bRow + wr * 64 + mi * 16 + fq * 4 + r;
        float v = acc[mi][ni][r] + bs;
        if (EPI == 1) v = 0.5f * v * (1.f + erff(v * 0.70710678118654752f));
        else if (EPI == 2) v = 1.f + 0.5f * ftanh(v);
        else if (EPI == 3) v = fmaxf(v, 0.f);
        else if (EPI == 5) v += bf2f(addend[row * N + col]);
        else if (EPI == 6) v = 0.5f * ftanh(v);
        if (EPI == 4) Cf[row * N + col] = v;
        else          Co[row * N + col] = f2bf(v);
      }
    }
  }
}

// ============ 256x256 / BK=64 / 4-merged-phase pipelined GEMM (round-9/13 proven) ============
// Final form: 16x16x32 MFMA (2-way LDS residual conflict = free); deeper pipelines
// spill at the 2-waves/SIMD 256-reg cap (r10-12); 32x32 shape 4-way-conflicts (r14).

#define RDA(buf, Qr) do { \
  _Pragma("unroll") for (int ks_ = 0; ks_ < 2; ++ks_) \
  _Pragma("unroll") for (int m_ = 0; m_ < 4; ++m_) \
    a[ks_][m_] = *(const bf16x8*)(ldsc + (buf) * 32768 + \
      ((Qr) * 128 + wr * 64 + m_ * 16 + fr) * 128 + ((ks_ * 64 + fq * 16) ^ swzc)); \
} while (0)

#define RDB(buf, Qc, bb) do { \
  _Pragma("unroll") for (int ks_ = 0; ks_ < 2; ++ks_) \
  _Pragma("unroll") for (int n_ = 0; n_ < 2; ++n_) \
    bb[ks_][n_] = *(const bf16x8*)(ldsc + 65536 + (buf) * 32768 + \
      ((Qc) * 128 + wc * 32 + n_ * 16 + fr) * 128 + ((ks_ * 64 + fq * 16) ^ swzc)); \
} while (0)

#define MM(Qr, Qc, bb) do { \
  __builtin_amdgcn_s_setprio(1); \
  _Pragma("unroll") for (int m_ = 0; m_ < 4; ++m_) \
  _Pragma("unroll") for (int n_ = 0; n_ < 2; ++n_) \
  _Pragma("unroll") for (int ks_ = 0; ks_ < 2; ++ks_) \
    acc[Qr][Qc][m_][n_] = __builtin_amdgcn_mfma_f32_16x16x32_bf16( \
        a[ks_][m_], bb[ks_][n_], acc[Qr][Qc][m_][n_], 0, 0, 0); \
  __builtin_amdgcn_s_setprio(0); \
} while (0)

#define STA(buf, tt, h) do { \
  _Pragma("unroll") for (int j_ = 0; j_ < 2; ++j_) \
    async16(aB + ((long)j_ * 64 + (h) * 128) * lda_l + (tt) * 64, \
            ldsc + (buf) * 32768 + (h) * 16384 + (j_ * 512 + tid) * 16); \
} while (0)

#define STB(buf, tt, h) do { \
  _Pragma("unroll") for (int j_ = 0; j_ < 2; ++j_) \
    async16(bB + ((long)j_ * 64 + (h) * 128) * K_l + (tt) * 64, \
            ldsc + 65536 + (buf) * 32768 + (h) * 16384 + (j_ * 512 + tid) * 16); \
} while (0)

template <int EPI>
__global__ __launch_bounds__(512, 2) void gemm256(const u16* __restrict__ A,
                                                  const u16* __restrict__ Bt,
                                                  const float* __restrict__ bias,
                                                  const u16* addend,
                                                  u16* Co, u16* Co2, float* Cf,
                                                  int N, int K, int lda, int ctLog) {
  extern __shared__ char ldsc[];
  const int tid = threadIdx.x;
  const int l = tid & 63;
  const int w = tid >> 6, wr = w >> 2, wc = w & 3;
  const int fr = l & 15, fq = l >> 4;
  const int swzc = (fr & 7) << 4;
  const long lda_l = lda, K_l = K;

  const int nwg = gridDim.x;
  const int orig = blockIdx.x;
  const int swz = (orig & 7) * (nwg >> 3) + (orig >> 3);
  const int rt = swz >> ctLog, ct = swz & ((1 << ctLog) - 1);
  const long bRow = (long)rt * 256, bCol = (long)ct * 256;
  const int NT = K >> 6;

  const int L0 = tid * 16;
  const int row0 = L0 >> 7;
  const int cswz = (L0 & 127) ^ ((row0 & 7) << 4);
  const u16* aB = A + (bRow + row0) * lda_l + (cswz >> 1);
  const u16* bB = Bt + (bCol + row0) * K_l + (cswz >> 1);

  f32x4 acc[2][2][4][2];
#pragma unroll
  for (int p = 0; p < 2; ++p)
#pragma unroll
    for (int qq = 0; qq < 2; ++qq)
#pragma unroll
      for (int m = 0; m < 4; ++m)
#pragma unroll
        for (int n = 0; n < 2; ++n) acc[p][qq][m][n] = (f32x4){0.f, 0.f, 0.f, 0.f};

  bf16x8 a[2][4], b0[2][2], b1[2][2];

  // prologue: tile0 full + tile1 A-h0, B-h1 (invariant: 4 loads in flight)
  STA(0, 0, 0); STA(0, 0, 1); STB(0, 0, 0); STB(0, 0, 1);
  STA(1, 1, 0); STB(1, 1, 1);
  WAITV(4);
  SBAR();

  for (int i = 0; i < (NT >> 1); ++i) {
    const int t0 = 2 * i, t1 = t0 + 1;
    const bool more = (t0 + 2) < NT;
    // phA: tile t0 (buf0) quadrants (0,0)+(0,1); stage t1's A-h1, B-h0
    RDA(0, 0); RDB(0, 0, b0); RDB(0, 1, b1);
    STA(1, t1, 1); STB(1, t1, 0);
    SBAR(); MM(0, 0, b0); MM(0, 1, b1); SBAR();
    // phB: quadrants (1,1)+(1,0); stage t0+2's A-h0, B-h1 into buf0
    RDA(0, 1);
    if (more) { STA(0, t0 + 2, 0); STB(0, t0 + 2, 1); }
    SBAR(); MM(1, 1, b1); MM(1, 0, b0);
    if (more) { WAITV(4); } else { WAITV(0); }   // tile t1 (buf1) complete
    SBAR();
    // phC: tile t1 (buf1) quadrants (0,0)+(0,1); stage t0+2's A-h1, B-h0
    RDA(1, 0); RDB(1, 0, b0); RDB(1, 1, b1);
    if (more) { STA(0, t0 + 2, 1); STB(0, t0 + 2, 0); }
    SBAR(); MM(0, 0, b0); MM(0, 1, b1); SBAR();
    // phD: quadrants (1,1)+(1,0); stage t1+2's A-h0, B-h1 into buf1
    RDA(1, 1);
    if (more) { STA(1, t1 + 2, 0); STB(1, t1 + 2, 1); }
    SBAR(); MM(1, 1, b1); MM(1, 0, b0);
    if (more) { WAITV(4); } else { WAITV(0); }   // tile t0+2 (buf0) complete
    SBAR();
  }

  // LDS-staged coalesced epilogue
  if (EPI != 4) {
    u16* dst = Co; long colBase = bCol; long strideW = N;
    if (EPI == 6) {
      strideW = 1024;
      if (bCol >= 1024) { dst = Co2; colBase = bCol - 1024; }
    }
    u16* lds16 = (u16*)ldsc;
#pragma unroll
    for (int Qr = 0; Qr < 2; ++Qr)
#pragma unroll
      for (int Qc = 0; Qc < 2; ++Qc)
#pragma unroll
        for (int n = 0; n < 2; ++n) {
          const int colL = Qc * 128 + wc * 32 + n * 16 + fr;
          const float bs = bias ? bias[bCol + colL] : 0.f;
#pragma unroll
          for (int m = 0; m < 4; ++m)
#pragma unroll
            for (int r = 0; r < 4; ++r) {
              const int rowL = Qr * 128 + wr * 64 + m * 16 + fq * 4 + r;
              float v = acc[Qr][Qc][m][n][r] + bs;
              if (EPI == 3) v = fmaxf(v, 0.f);
              lds16[rowL * 256 + colL] = f2bf(v);
            }
        }
    __syncthreads();
    const int rB = tid >> 5, cL = (tid & 31) * 8;
#pragma unroll
    for (int it = 0; it < 16; ++it) {
      const int rL = it * 16 + rB;
      const long gr = bRow + rL;
      u16x8 sv = *(const u16x8*)(lds16 + rL * 256 + cL);
      if (EPI == 5) {
        u16x8 ad = *(const u16x8*)(addend + gr * (long)N + bCol + cL);
#pragma unroll
        for (int j = 0; j < 8; ++j) sv[j] = f2bf(bf2f(sv[j]) + bf2f(ad[j]));
      }
      *(u16x8*)(dst + gr * strideW + colBase + cL) = sv;
    }
  } else {
    float* ldsf = (float*)ldsc;
#pragma unroll
    for (int p = 0; p < 2; ++p) {
#pragma unroll
      for (int Qc = 0; Qc < 2; ++Qc)
#pragma unroll
        for (int n = 0; n < 2; ++n) {
          const int colL = Qc * 128 + wc * 32 + n * 16 + fr;
          const float bs = bias ? bias[bCol + colL] : 0.f;
#pragma unroll
          for (int m = 0; m < 4; ++m)
#pragma unroll
            for (int r = 0; r < 4; ++r) {
              const int rowL = wr * 64 + m * 16 + fq * 4 + r;
              ldsf[rowL * 256 + colL] = acc[p][Qc][m][n][r] + bs;
            }
        }
      __syncthreads();
      const int c4 = (tid & 63) * 4, rB = tid >> 6;
#pragma unroll
      for (int it = 0; it < 16; ++it) {
        const int rL = it * 8 + rB;
        const long gr = bRow + p * 128 + rL;
        float4 fv = *(const float4*)(ldsf + rL * 256 + c4);
        *(float4*)(Cf + gr * (long)N + bCol + c4) = fv;
      }
      __syncthreads();
    }
  }
}

// ---------------- attention, 4 heads per 256-thread block; o may alias q ----------------
__global__ __launch_bounds__(256) void attn4_kernel(const u16* q,
                                                    const u16* __restrict__ k,
                                                    const u16* __restrict__ v,
                                                    u16* o) {
  const int tid = threadIdx.x;
  const int wid = tid >> 6, l = tid & 63;
  const int bh = blockIdx.x * 4 + wid;
  const int b = bh >> 3, hd = bh & 7;
  const long base = (long)b * 32 * 1024 + hd * 128;
  const int lo = l & 31, hi = l >> 5;
  __shared__ u16 P[4][32 * 36];
  __shared__ u16 Vt[4][128 * 36];
  u16* Pw = P[wid];
  u16* Vw = Vt[wid];

#pragma unroll
  for (int i = 0; i < 8; ++i) {
    int idx = i * 64 + l;
    int tok = idx >> 4, d0 = (idx & 15) * 8;
    const u16* src = v + base + (long)tok * 1024 + d0;
    ushort4 a0 = *(const ushort4*)src;
    ushort4 a1 = *(const ushort4*)(src + 4);
    u16 vals[8] = {a0.x, a0.y, a0.z, a0.w, a1.x, a1.y, a1.z, a1.w};
#pragma unroll
    for (int j = 0; j < 8; ++j) Vw[(d0 + j) * 36 + tok] = vals[j];
  }

  f32x16 st;
#pragma unroll
  for (int r = 0; r < 16; ++r) st[r] = 0.f;
#pragma unroll
  for (int kb = 0; kb < 8; ++kb) {
    bf16x8 kf = *(const bf16x8*)(k + base + (long)lo * 1024 + kb * 16 + hi * 8);
    bf16x8 qf = *(const bf16x8*)(q + base + (long)lo * 1024 + kb * 16 + hi * 8);
    st = __builtin_amdgcn_mfma_f32_32x32x16_bf16(kf, qf, st, 0, 0, 0);
  }
  float mx = -1e30f;
#pragma unroll
  for (int r = 0; r < 16; ++r) { st[r] *= 0.08838834764831845f; mx = fmaxf(mx, st[r]); }
  mx = fmaxf(mx, __shfl_xor(mx, 32));
  float p[16], sum = 0.f;
#pragma unroll
  for (int r = 0; r < 16; ++r) { p[r] = __expf(st[r] - mx); sum += p[r]; }
  sum += __shfl_xor(sum, 32);
  const float inv = 1.f / sum;
#pragma unroll
  for (int r = 0; r < 16; ++r) {
    int kt = (r & 3) + 8 * (r >> 2) + 4 * hi;
    Pw[lo * 36 + kt] = f2bf(p[r] * inv);
  }
  __syncthreads();

#pragma unroll
  for (int nb = 0; nb < 4; ++nb) {
    f32x16 oa;
#pragma unroll
    for (int r = 0; r < 16; ++r) oa[r] = 0.f;
#pragma unroll
    for (int ks = 0; ks < 2; ++ks) {
      union { bf16x8 v8; ushort4 h[2]; } pa, vb;
      pa.h[0] = *(const ushort4*)&Pw[lo * 36 + ks * 16 + hi * 8];
      pa.h[1] = *(const ushort4*)&Pw[lo * 36 + ks * 16 + hi * 8 + 4];
      vb.h[0] = *(const ushort4*)&Vw[(nb * 32 + lo) * 36 + ks * 16 + hi * 8];
      vb.h[1] = *(const ushort4*)&Vw[(nb * 32 + lo) * 36 + ks * 16 + hi * 8 + 4];
      oa = __builtin_amdgcn_mfma_f32_32x32x16_bf16(pa.v8, vb.v8, oa, 0, 0, 0);
    }
#pragma unroll
    for (int r = 0; r < 16; ++r) {
      int qrow = (r & 3) + 8 * (r >> 2) + 4 * hi;
      o[base + (long)qrow * 1024 + nb * 32 + lo] = f2bf(oa[r]);
    }
  }
}

// ---------------- launch ----------------
extern "C" void kernel_launch(void* const* d_in, const int* in_sizes, int n_in,
                              void* d_out, int out_size, void* d_ws, size_t ws_size,
                              hipStream_t stream) {
  const float* state = (const float*)d_in[0];  const float* cond  = (const float*)d_in[1];
  const float* ew1 = (const float*)d_in[2];    const float* eb1 = (const float*)d_in[3];
  const float* eg1 = (const float*)d_in[4];    const float* ebt1 = (const float*)d_in[5];
  const float* ew2 = (const float*)d_in[6];    const float* eb2 = (const float*)d_in[7];
  const float* eg2 = (const float*)d_in[8];    const float* ebt2 = (const float*)d_in[9];
  const float* rw = (const float*)d_in[10];    const float* rb = (const float*)d_in[11];
  const float* fw1 = (const float*)d_in[12];   const float* fb1 = (const float*)d_in[13];
  const float* fw2 = (const float*)d_in[14];   const float* fb2 = (const float*)d_in[15];
  const float* lnq_g = (const float*)d_in[16]; const float* lnq_b = (const float*)d_in[17];
  const float* wq = (const float*)d_in[18];    const float* wk = (const float*)d_in[19];
  const float* wv = (const float*)d_in[20];    const float* wo = (const float*)d_in[21];
  const float* cn_g = (const float*)d_in[22];  const float* cn_b = (const float*)d_in[23];
  const float* hw1 = (const float*)d_in[24];   const float* hb1 = (const float*)d_in[25];
  const float* hw2 = (const float*)d_in[26];   const float* hb2 = (const float*)d_in[27];

  const size_t MB128 = 134217728ULL;
  const size_t WT_BYTES = 17367040ULL;
  const size_t FH_BYTES = 16777216ULL;
  char* ws = (char*)d_ws;
  u16* OUTu = (u16*)d_out;
  float* OUTf = (float*)d_out;

  (void)hipFuncSetAttribute((const void*)gemm256<0>, hipFuncAttributeMaxDynamicSharedMemorySize, 131072);
  (void)hipFuncSetAttribute((const void*)gemm256<3>, hipFuncAttributeMaxDynamicSharedMemorySize, 131072);
  (void)hipFuncSetAttribute((const void*)gemm256<4>, hipFuncAttributeMaxDynamicSharedMemorySize, 131072);
  (void)hipFuncSetAttribute((const void*)gemm256<5>, hipFuncAttributeMaxDynamicSharedMemorySize, 131072);
  (void)hipFuncSetAttribute((const void*)gemm256<6>, hipFuncAttributeMaxDynamicSharedMemorySize, 131072);
  (void)hipFuncSetAttribute((const void*)film_qin,   hipFuncAttributeMaxDynamicSharedMemorySize, 73984);

  u16* wt = nullptr;
  bool planA = false;
  int R = 0;
  if (ws_size >= 3 * MB128 + FH_BYTES + WT_BYTES) {
    planA = true;
    wt = (u16*)(ws + 3 * MB128 + FH_BYTES);
  } else {
    for (int r = 8192; r >= 1024; r >>= 1) {
      size_t need = 2 * MB128 + (size_t)r * 8448ULL + WT_BYTES;
      if (ws_size >= need) { R = r; wt = (u16*)(ws + 2 * MB128 + (size_t)r * 8448ULL); break; }
    }
    if (!R) return;
  }

  u16* ew1T = wt + 0;        u16* rwT  = wt + 786432;  u16* ew2T = wt + 1572864;
  u16* fw1T = wt + 2621440;  u16* fw2T = wt + 2654208;
  u16* wqT  = wt + 2916352;  u16* wkT  = wt + 3964928; u16* wvT  = wt + 5013504;
  u16* woT  = wt + 6062080;  u16* hw1T = wt + 7110656; u16* hw2T = wt + 8159232;

  if (planA) {
    u16* S1 = (u16*)ws;
    u16* S2 = (u16*)(ws + MB128);
    u16* S3 = (u16*)(ws + 2 * MB128);
    u16* FH = (u16*)(ws + 3 * MB128);

    WSrc src;
    src.p[0] = ew1; src.p[1] = rw;  src.p[2] = ew2; src.p[3] = fw1; src.p[4] = fw2;
    src.p[5] = wq;  src.p[6] = wk;  src.p[7] = wv;  src.p[8] = wo;  src.p[9] = hw1;
    src.p[10] = hw2;
    init_kernel<<<57632, 256, 0, stream>>>(src, wt, state, cond, S1);

    gemm_bt<1><<<dim3(512, 1), 256, 0, stream>>>(S1 + 512, fw1T, fb1, nullptr, FH, nullptr, 128, 256, 768);
    gemm256<0><<<1024, 512, 131072, stream>>>(S1, ew1T, eb1, nullptr, S2, nullptr, nullptr, 1024, 768, 768, 2);   // y1=S2
    ln_relu_w<<<16384, 256, 0, stream>>>(S2, eg1, ebt1, S2);                                   // h1=S2
    gemm256<0><<<1024, 512, 131072, stream>>>(S2, ew2T, eb2, nullptr, S3, nullptr, nullptr, 1024, 1024, 1024, 2); // y2=S3
    ln_relu_w<<<16384, 256, 0, stream>>>(S3, eg2, ebt2, S3);                                   // hbf=S3
    film_qin<<<2048, 256, 73984, stream>>>(S3, FH, fw2T, fb2, lnq_g, lnq_b, OUTu);             // qin=OUT
    gemm256<0><<<1024, 512, 131072, stream>>>(OUTu, wqT, nullptr, nullptr, S1, nullptr, nullptr, 1024, 1024, 1024, 2); // q=S1
    gemm256<6><<<2048, 512, 131072, stream>>>(S3, wkT, nullptr, nullptr, S2, OUTu, nullptr, 2048, 1024, 1024, 3);      // k=S2, v=OUT
    attn4_kernel<<<4096, 256, 0, stream>>>(S1, S2, OUTu, S1);                                  // o=S1
    prep_kernel<<<49152, 256, 0, stream>>>(state, cond, S2);                                   // xb2=S2
    gemm256<0><<<1024, 512, 131072, stream>>>(S2, rwT, rb, nullptr, OUTu, nullptr, nullptr, 1024, 768, 768, 2);   // res=OUT
    gemm256<5><<<1024, 512, 131072, stream>>>(S1, woT, nullptr, OUTu, OUTu, nullptr, nullptr, 1024, 1024, 1024, 2); // o2=OUT
    h2_w<<<16384, 256, 0, stream>>>(S3, OUTu, cn_g, cn_b, S1);                                 // h2=S1
    gemm256<3><<<1024, 512, 131072, stream>>>(S1, hw1T, hb1, nullptr, S2, nullptr, nullptr, 1024, 1024, 1024, 2); // mh=S2
    gemm256<4><<<512, 512, 131072, stream>>>(S2, hw2T, hb2, nullptr, nullptr, nullptr, OUTf, 512, 1024, 1024, 1);
    return;
  }

  // ---- Plan C: chunked fallback ----
  transpose_cvt<<<dim3(32, 24), 256, 0, stream>>>(ew1, ew1T, 768, 1024);
  transpose_cvt<<<dim3(32, 24), 256, 0, stream>>>(rw,  rwT,  768, 1024);
  transpose_cvt<<<dim3(32, 32), 256, 0, stream>>>(ew2, ew2T, 1024, 1024);
  transpose_cvt<<<dim3(4, 8),   256, 0, stream>>>(fw1, fw1T, 256, 128);
  transpose_cvt<<<dim3(64, 4),  256, 0, stream>>>(fw2, fw2T, 128, 2048);
  transpose_cvt<<<dim3(32, 32), 256, 0, stream>>>(wq, wqT, 1024, 1024);
  transpose_cvt<<<dim3(32, 32), 256, 0, stream>>>(wk, wkT, 1024, 1024);
  transpose_cvt<<<dim3(32, 32), 256, 0, stream>>>(wv, wvT, 1024, 1024);
  transpose_cvt<<<dim3(32, 32), 256, 0, stream>>>(wo, woT, 1024, 1024);
  transpose_cvt<<<dim3(32, 32), 256, 0, stream>>>(hw1, hw1T, 1024, 1024);
  transpose_cvt<<<dim3(16, 32), 256, 0, stream>>>(hw2, hw2T, 1024, 512);

  u16* F1 = (u16*)ws;
  u16* F2 = (u16*)(ws + MB128);
  char* g = ws + 2 * MB128;
  u16* G0 = (u16*)g;
  u16* G1 = (u16*)(g + (size_t)R * 2048);
  u16* G2 = (u16*)(g + (size_t)R * 4096);
  u16* G3 = (u16*)(g + (size_t)R * 4096 + (size_t)R * 256);
  u16* G4 = (u16*)(g + (size_t)R * 6144 + (size_t)R * 256);
  const int GX = R / 128, CH = 65536 / R;

  for (int c = 0; c < CH; ++c) {
    const long r0 = (long)c * R;
    prep_kernel<<<R * 3 / 4, 256, 0, stream>>>(state + r0 * 512, cond + r0 * 256, G0);
    gemm_bt<1><<<dim3(GX, 1), 256, 0, stream>>>(G0 + 512, fw1T, fb1, nullptr, G2, nullptr, 128, 256, 768);
    gemm_bt<0><<<dim3(GX, 8), 256, 0, stream>>>(G0, ew1T, eb1, nullptr, G1, nullptr, 1024, 768, 768);
    gemm_bt<0><<<dim3(GX, 8), 256, 0, stream>>>(G0, rwT,  rb,  nullptr, F2 + r0 * 1024, nullptr, 1024, 768, 768);
    ln_relu_w<<<R / 4, 256, 0, stream>>>(G1, eg1, ebt1, G3);
    gemm_bt<0><<<dim3(GX, 8), 256, 0, stream>>>(G3, ew2T, eb2, nullptr, G0, nullptr, 1024, 1024, 1024);
    ln_relu_w<<<R / 4, 256, 0, stream>>>(G0, eg2, ebt2, F1 + r0 * 1024);
    gemm_bt<2><<<dim3(GX, 8), 256, 0, stream>>>(G2, fw2T, fb2, nullptr, G3, nullptr, 1024, 128, 128);
    gemm_bt<6><<<dim3(GX, 8), 256, 0, stream>>>(G2, fw2T + 131072, fb2 + 1024, nullptr, G1, nullptr, 1024, 128, 128);
    qin_sep_kernel<<<R, 256, 0, stream>>>(F1 + r0 * 1024, G3, G1, lnq_g, lnq_b, G3);
    gemm_bt<0><<<dim3(GX, 8), 256, 0, stream>>>(G3, wqT, nullptr, nullptr, G0, nullptr, 1024, 1024, 1024);
    gemm_bt<0><<<dim3(GX, 8), 256, 0, stream>>>(F1 + r0 * 1024, wkT, nullptr, nullptr, G1, nullptr, 1024, 1024, 1024);
    gemm_bt<0><<<dim3(GX, 8), 256, 0, stream>>>(F1 + r0 * 1024, wvT, nullptr, nullptr, G4, nullptr, 1024, 1024, 1024);
    attn4_kernel<<<R / 16, 256, 0, stream>>>(G0, G1, G4, G0);
    gemm_bt<5><<<dim3(GX, 8), 256, 0, stream>>>(G0, woT, nullptr, F2 + r0 * 1024, F2 + r0 * 1024, nullptr, 1024, 1024, 1024);
  }
  h2_w<<<16384, 256, 0, stream>>>(F1, F2, cn_g, cn_b, OUTu);
  gemm_bt<3><<<dim3(512, 8), 256, 0, stream>>>(OUTu, hw1T, hb1, nullptr, F1, nullptr, 1024, 1024, 1024);
  gemm_bt<4><<<dim3(512, 4), 256, 0, stream>>>(F1, hw2T, hb2, nullptr, nullptr, OUTf, 512, 1024, 1024);
}